// Round 7
// baseline (455.739 us; speedup 1.0000x reference)
//
#include <hip/hip_runtime.h>
#include <hip/hip_bf16.h>

#define NN 320
#define CC 128
#define HH 4
#define CHD 32
#define HC 128
#define NP (NN*NN)

typedef __hip_bfloat16 bf16;
typedef __bf16 bfv8 __attribute__((ext_vector_type(8)));
typedef float fv4 __attribute__((ext_vector_type(4)));

__device__ __forceinline__ unsigned short bfbits(float f) {
    bf16 h = __float2bfloat16(f);
    return *reinterpret_cast<unsigned short*>(&h);
}

// ---------------- K0: weight convert/transpose to bf16 ----------------
__global__ __launch_bounds__(256) void k_wconv(
    const float* __restrict__ wq, const float* __restrict__ wk,
    const float* __restrict__ wv, const float* __restrict__ wg,
    const float* __restrict__ wo, const float* __restrict__ w_bias,
    bf16* __restrict__ wt, bf16* __restrict__ wot, bf16* __restrict__ wtb)
{
    __shared__ unsigned short T[128 * 136];
    const int b = blockIdx.x, t = threadIdx.x;
    if (b < 5) {
        const float* W = (b == 0) ? wq : (b == 1) ? wk : (b == 2) ? wv : (b == 3) ? wg : wo;
        bf16* D = (b < 4) ? (wt + b * 16384) : wot;
        const float scale = (b == 0) ? 0.17677669529663687f : 1.0f;
        for (int idx = t; idx < 16384; idx += 256) {
            int c = idx >> 7, out = idx & 127;
            T[out * 136 + c] = bfbits(W[idx] * scale);
        }
        __syncthreads();
        for (int i8 = t; i8 < 2048; i8 += 256) {
            int out = i8 >> 4, c0 = (i8 & 15) * 8;
            uint4 v = *reinterpret_cast<const uint4*>(&T[out * 136 + c0]);
            *reinterpret_cast<uint4*>(D + out * 128 + c0) = v;
        }
    } else {
        int out = t >> 4, c0 = (t & 15) * 8;
        unsigned short vals[8];
#pragma unroll
        for (int j = 0; j < 8; j++)
            vals[j] = (out < 4) ? bfbits(w_bias[(c0 + j) * 4 + out]) : (unsigned short)0;
        *reinterpret_cast<uint4*>(wtb + out * 128 + c0) = *reinterpret_cast<uint4*>(vals);
    }
}

// ---------------- K1: LN + MFMA projections + tri_bias ----------------
__global__ __launch_bounds__(256) void k_proj(
    const float* __restrict__ x, const float* __restrict__ ln_g, const float* __restrict__ ln_b,
    const bf16* __restrict__ wt, const bf16* __restrict__ wtb, const float* __restrict__ bg,
    bf16* __restrict__ qo, bf16* __restrict__ ko, bf16* __restrict__ vo, bf16* __restrict__ go,
    float* __restrict__ tri)
{
    __shared__ unsigned short A[128 * 136];
    const int t = threadIdx.x;
    const int wv = t >> 6, lane = t & 63, g = lane >> 4, c = lane & 15;
    const size_t pb = (size_t)blockIdx.x * 128;

#pragma unroll
    for (int rnd = 0; rnd < 2; rnd++) {
        const int p = (t >> 2) + rnd * 64, l = t & 3;
        const float* xr = x + (pb + p) * CC + l * 32;
        float4 xv[8];
#pragma unroll
        for (int i = 0; i < 8; i++) xv[i] = reinterpret_cast<const float4*>(xr)[i];
        float s = 0.f, s2 = 0.f;
#pragma unroll
        for (int i = 0; i < 8; i++) {
            s  += xv[i].x + xv[i].y + xv[i].z + xv[i].w;
            s2 += xv[i].x * xv[i].x + xv[i].y * xv[i].y + xv[i].z * xv[i].z + xv[i].w * xv[i].w;
        }
        s  += __shfl_xor(s, 1, 4);  s  += __shfl_xor(s, 2, 4);
        s2 += __shfl_xor(s2, 1, 4); s2 += __shfl_xor(s2, 2, 4);
        float mu = s * (1.f / CC);
        float var = s2 * (1.f / CC) - mu * mu;
        float rstd = rsqrtf(var + 1e-5f);
        const float4* gr = reinterpret_cast<const float4*>(ln_g + l * 32);
        const float4* br = reinterpret_cast<const float4*>(ln_b + l * 32);
#pragma unroll
        for (int i = 0; i < 8; i += 2) {
            float4 g0 = gr[i], g1 = gr[i + 1], b0 = br[i], b1 = br[i + 1];
            uint4 pk;
            pk.x = (unsigned)bfbits((xv[i].x - mu) * rstd * g0.x + b0.x)
                 | ((unsigned)bfbits((xv[i].y - mu) * rstd * g0.y + b0.y) << 16);
            pk.y = (unsigned)bfbits((xv[i].z - mu) * rstd * g0.z + b0.z)
                 | ((unsigned)bfbits((xv[i].w - mu) * rstd * g0.w + b0.w) << 16);
            pk.z = (unsigned)bfbits((xv[i+1].x - mu) * rstd * g1.x + b1.x)
                 | ((unsigned)bfbits((xv[i+1].y - mu) * rstd * g1.y + b1.y) << 16);
            pk.w = (unsigned)bfbits((xv[i+1].z - mu) * rstd * g1.z + b1.z)
                 | ((unsigned)bfbits((xv[i+1].w - mu) * rstd * g1.w + b1.w) << 16);
            *reinterpret_cast<uint4*>(&A[p * 136 + l * 32 + i * 4]) = pk;
        }
    }
    __syncthreads();

    bfv8 bx[2][4];
#pragma unroll
    for (int tile = 0; tile < 2; tile++)
#pragma unroll
        for (int kc = 0; kc < 4; kc++)
            bx[tile][kc] = *reinterpret_cast<const bfv8*>(
                &A[(wv * 32 + tile * 16 + c) * 136 + kc * 32 + 8 * g]);

    fv4 zero = {0.f, 0.f, 0.f, 0.f};

    {
        fv4 at0 = zero, at1 = zero;
#pragma unroll
        for (int kc = 0; kc < 4; kc++) {
            bfv8 bb = *reinterpret_cast<const bfv8*>(wtb + c * 128 + kc * 32 + 8 * g);
            at0 = __builtin_amdgcn_mfma_f32_16x16x32_bf16(bx[0][kc], bb, at0, 0, 0, 0);
            at1 = __builtin_amdgcn_mfma_f32_16x16x32_bf16(bx[1][kc], bb, at1, 0, 0, 0);
        }
        if (c < HH) {
            float4 s0 = {at0[0], at0[1], at0[2], at0[3]};
            float4 s1 = {at1[0], at1[1], at1[2], at1[3]};
            float* tb = tri + (size_t)c * NP + pb + wv * 32 + 4 * g;
            *reinterpret_cast<float4*>(tb)      = s0;
            *reinterpret_cast<float4*>(tb + 16) = s1;
        }
    }

    bf16* Os[4] = {qo, ko, vo, go};
#pragma unroll 1
    for (int m = 0; m < 4; m++) {
        const bf16* WtM = wt + m * 16384;
        fv4 acc[2][8];
#pragma unroll
        for (int n = 0; n < 8; n++) { acc[0][n] = zero; acc[1][n] = zero; }
#pragma unroll
        for (int n = 0; n < 8; n++)
#pragma unroll
            for (int kc = 0; kc < 4; kc++) {
                bfv8 bw = *reinterpret_cast<const bfv8*>(WtM + (n * 16 + c) * 128 + kc * 32 + 8 * g);
                acc[0][n] = __builtin_amdgcn_mfma_f32_16x16x32_bf16(bw, bx[0][kc], acc[0][n], 0, 0, 0);
                acc[1][n] = __builtin_amdgcn_mfma_f32_16x16x32_bf16(bw, bx[1][kc], acc[1][n], 0, 0, 0);
            }
        if (m == 3) {
#pragma unroll
            for (int n = 0; n < 8; n++) {
                float4 bgv = *reinterpret_cast<const float4*>(bg + n * 16 + 4 * g);
                float bgs[4] = {bgv.x, bgv.y, bgv.z, bgv.w};
#pragma unroll
                for (int tile = 0; tile < 2; tile++)
#pragma unroll
                    for (int r = 0; r < 4; r++) {
                        float z = acc[tile][n][r] + bgs[r];
                        acc[tile][n][r] = 1.f / (1.f + __expf(-z));
                    }
            }
        }
        bf16* O = Os[m];
#pragma unroll
        for (int tile = 0; tile < 2; tile++)
#pragma unroll
            for (int n = 0; n < 8; n++) {
                uint2 pk;
                pk.x = (unsigned)bfbits(acc[tile][n][0]) | ((unsigned)bfbits(acc[tile][n][1]) << 16);
                pk.y = (unsigned)bfbits(acc[tile][n][2]) | ((unsigned)bfbits(acc[tile][n][3]) << 16);
                *reinterpret_cast<uint2*>(O + (pb + wv * 32 + tile * 16 + c) * HC + n * 16 + 4 * g) = pk;
            }
    }
}

// ---------------- K2: MFMA attention, one block per (i,h) ----------------
// K,V^T staged to LDS once; P stays in registers (shuffle-based B-frag build).
__global__ __launch_bounds__(256) void k_attn(
    const bf16* __restrict__ qi, const bf16* __restrict__ ki, const bf16* __restrict__ vi,
    const bf16* __restrict__ gi, const float* __restrict__ mask, const float* __restrict__ tri,
    bf16* __restrict__ oo)
{
    __shared__ unsigned short Ks[320 * 40];   // K[key][dim], stride 40 shorts
    __shared__ unsigned short Vt[32 * 368];   // V^T[dim][key], rot 16*(dim>>3)
    __shared__ float mb[320];                 // mask bias row

    const int t = threadIdx.x;
    const int wv = t >> 6, lane = t & 63, g = lane >> 4, c = lane & 15;
    const int h = blockIdx.x, i = blockIdx.y;
    const size_t rowbase = (size_t)i * NN;

    // ---- stage K and V^T once per (i,h) ----
#pragma unroll
    for (int it = 0; it < 5; it++) {
        int ci = it * 256 + t;
        int key = ci >> 2, d0 = (ci & 3) * 8;
        uint4 kv = *reinterpret_cast<const uint4*>(ki + (rowbase + key) * HC + h * CHD + d0);
        *reinterpret_cast<uint4*>(&Ks[key * 40 + d0]) = kv;
        uint4 vv = *reinterpret_cast<const uint4*>(vi + (rowbase + key) * HC + h * CHD + d0);
        unsigned wd[4] = {vv.x, vv.y, vv.z, vv.w};
#pragma unroll
        for (int u = 0; u < 4; u++) {
            int r0 = d0 + 2 * u, r1 = r0 + 1;
            Vt[r0 * 368 + key + 16 * (r0 >> 3)] = (unsigned short)(wd[u] & 0xffffu);
            Vt[r1 * 368 + key + 16 * (r1 >> 3)] = (unsigned short)(wd[u] >> 16);
        }
    }
    for (int k0 = t; k0 < 320; k0 += 256)
        mb[k0] = 1.0e9f * (mask[rowbase + k0] - 1.0f);
    __syncthreads();

    fv4 zero = {0.f, 0.f, 0.f, 0.f};

#pragma unroll 1
    for (int iter = 0; iter < 5; iter++) {
        const int qb = iter * 64 + wv * 16;
        bfv8 bq = *reinterpret_cast<const bfv8*>(qi + (rowbase + qb + c) * HC + h * CHD + 8 * g);
        const float* trirow = tri + (size_t)h * NP + (size_t)(qb + c) * NN;

        // ---- scores S^T: D[key][q], lane: q=c, keys kt*16+4g+r ----
        float s[20][4];
#pragma unroll
        for (int kt = 0; kt < 20; kt++) {
            bfv8 ak = *reinterpret_cast<const bfv8*>(&Ks[(kt * 16 + c) * 40 + 8 * g]);
            fv4 sa = __builtin_amdgcn_mfma_f32_16x16x32_bf16(ak, bq, zero, 0, 0, 0);
            float4 tr = *reinterpret_cast<const float4*>(trirow + kt * 16 + 4 * g);
            float4 mk = *reinterpret_cast<const float4*>(&mb[kt * 16 + 4 * g]);
            s[kt][0] = sa[0] + tr.x + mk.x;
            s[kt][1] = sa[1] + tr.y + mk.y;
            s[kt][2] = sa[2] + tr.z + mk.z;
            s[kt][3] = sa[3] + tr.w + mk.w;
        }

        // ---- softmax over keys ----
        float mx = -3.0e38f;
#pragma unroll
        for (int kt = 0; kt < 20; kt++)
#pragma unroll
            for (int r = 0; r < 4; r++) mx = fmaxf(mx, s[kt][r]);
        mx = fmaxf(mx, __shfl_xor(mx, 16, 64));
        mx = fmaxf(mx, __shfl_xor(mx, 32, 64));
        float sm = 0.f;
        unsigned pk[20][2];
#pragma unroll
        for (int kt = 0; kt < 20; kt++) {
            float e0 = __expf(s[kt][0] - mx);
            float e1 = __expf(s[kt][1] - mx);
            float e2 = __expf(s[kt][2] - mx);
            float e3 = __expf(s[kt][3] - mx);
            sm += (e0 + e1) + (e2 + e3);
            pk[kt][0] = (unsigned)bfbits(e0) | ((unsigned)bfbits(e1) << 16);
            pk[kt][1] = (unsigned)bfbits(e2) | ((unsigned)bfbits(e3) << 16);
        }
        sm += __shfl_xor(sm, 16, 64);
        sm += __shfl_xor(sm, 32, 64);
        float linv = 1.f / sm;

        // ---- PV: O^T = V^T @ P^T; B-frag built via cross-lane shuffles ----
        fv4 o0 = zero, o1 = zero;
#pragma unroll
        for (int s2 = 0; s2 < 10; s2++) {
            unsigned bpw[4];
#pragma unroll
            for (int p = 0; p < 4; p++) {
                int src = ((g & 1) * 2 + (p >> 1)) * 16 + c;
                int v0 = __shfl((int)pk[2 * s2][p & 1], src, 64);
                int v1 = __shfl((int)pk[2 * s2 + 1][p & 1], src, 64);
                bpw[p] = (unsigned)((g < 2) ? v0 : v1);
            }
            uint4 bpv = {bpw[0], bpw[1], bpw[2], bpw[3]};
            bfv8 bp = *reinterpret_cast<bfv8*>(&bpv);
            bfv8 av0 = *reinterpret_cast<const bfv8*>(&Vt[c * 368 + s2 * 32 + 8 * g + 16 * (c >> 3)]);
            bfv8 av1 = *reinterpret_cast<const bfv8*>(&Vt[(16 + c) * 368 + s2 * 32 + 8 * g + 32 + 16 * (c >> 3)]);
            o0 = __builtin_amdgcn_mfma_f32_16x16x32_bf16(av0, bp, o0, 0, 0, 0);
            o1 = __builtin_amdgcn_mfma_f32_16x16x32_bf16(av1, bp, o1, 0, 0, 0);
        }

        // ---- epilogue ----
        size_t obase = (rowbase + qb + c) * HC + h * CHD;
#pragma unroll
        for (int mt = 0; mt < 2; mt++) {
            fv4 oc = mt ? o1 : o0;
            int d0 = mt * 16 + 4 * g;
            uint2 gg = *reinterpret_cast<const uint2*>(gi + obase + d0);
            float gf0 = __uint_as_float(gg.x << 16);
            float gf1 = __uint_as_float(gg.x & 0xffff0000u);
            float gf2 = __uint_as_float(gg.y << 16);
            float gf3 = __uint_as_float(gg.y & 0xffff0000u);
            uint2 st;
            st.x = (unsigned)bfbits(oc[0] * linv * gf0) | ((unsigned)bfbits(oc[1] * linv * gf1) << 16);
            st.y = (unsigned)bfbits(oc[2] * linv * gf2) | ((unsigned)bfbits(oc[3] * linv * gf3) << 16);
            *reinterpret_cast<uint2*>(oo + obase + d0) = st;
        }
    }
}

// ---------------- K3: MFMA output projection (fp32 out) ----------------
__global__ __launch_bounds__(256) void k_out(
    const bf16* __restrict__ oi, const bf16* __restrict__ wot, const float* __restrict__ bo,
    float* __restrict__ outp)
{
    const int t = threadIdx.x;
    const int wv = t >> 6, lane = t & 63, g = lane >> 4, c = lane & 15;
    const size_t pb = (size_t)blockIdx.x * 64;

    bfv8 bx[4];
#pragma unroll
    for (int kc = 0; kc < 4; kc++)
        bx[kc] = *reinterpret_cast<const bfv8*>(oi + (pb + wv * 16 + c) * HC + kc * 32 + 8 * g);

    fv4 zero = {0.f, 0.f, 0.f, 0.f};
    fv4 acc[8];
#pragma unroll
    for (int n = 0; n < 8; n++) acc[n] = zero;
#pragma unroll
    for (int n = 0; n < 8; n++)
#pragma unroll
        for (int kc = 0; kc < 4; kc++) {
            bfv8 bw = *reinterpret_cast<const bfv8*>(wot + (n * 16 + c) * 128 + kc * 32 + 8 * g);
            acc[n] = __builtin_amdgcn_mfma_f32_16x16x32_bf16(bw, bx[kc], acc[n], 0, 0, 0);
        }
#pragma unroll
    for (int n = 0; n < 8; n++) {
        float4 b4 = *reinterpret_cast<const float4*>(bo + n * 16 + 4 * g);
        float4 st;
        st.x = acc[n][0] + b4.x;
        st.y = acc[n][1] + b4.y;
        st.z = acc[n][2] + b4.z;
        st.w = acc[n][3] + b4.w;
        *reinterpret_cast<float4*>(outp + (pb + wv * 16 + c) * CC + n * 16 + 4 * g) = st;
    }
}

extern "C" void kernel_launch(void* const* d_in, const int* in_sizes, int n_in,
                              void* d_out, int out_size, void* d_ws, size_t ws_size,
                              hipStream_t stream) {
    const float* x      = (const float*)d_in[0];
    const float* mask   = (const float*)d_in[1];
    const float* ln_g   = (const float*)d_in[2];
    const float* ln_b   = (const float*)d_in[3];
    const float* w_bias = (const float*)d_in[4];
    const float* wq     = (const float*)d_in[5];
    const float* wk     = (const float*)d_in[6];
    const float* wv     = (const float*)d_in[7];
    const float* wg     = (const float*)d_in[8];
    const float* bg     = (const float*)d_in[9];
    const float* wo     = (const float*)d_in[10];
    const float* bo     = (const float*)d_in[11];
    float* outp = (float*)d_out;

    bf16* qws = (bf16*)d_ws;
    bf16* kws = qws + (size_t)NP*HC;
    bf16* vws = kws + (size_t)NP*HC;
    bf16* gws = vws + (size_t)NP*HC;
    bf16* ows = gws + (size_t)NP*HC;
    float* tri = (float*)(ows + (size_t)NP*HC);
    bf16* wt  = (bf16*)(tri + (size_t)NP*HH);
    bf16* wot = wt + 4 * 16384;
    bf16* wtb = wot + 16384;

    hipLaunchKernelGGL(k_wconv, dim3(6), dim3(256), 0, stream,
                       wq, wk, wv, wg, wo, w_bias, wt, wot, wtb);
    hipLaunchKernelGGL(k_proj, dim3(NP/128), dim3(256), 0, stream,
                       x, ln_g, ln_b, wt, wtb, bg, qws, kws, vws, gws, tri);
    hipLaunchKernelGGL(k_attn, dim3(HH, NN), dim3(256), 0, stream,
                       qws, kws, vws, gws, mask, tri, ows);
    hipLaunchKernelGGL(k_out, dim3(NP/64), dim3(256), 0, stream,
                       ows, wot, bo, outp);
}